// Round 15
// baseline (273.136 us; speedup 1.0000x reference)
//
#include <hip/hip_runtime.h>
#include <hip/hip_bf16.h>
#include <stdint.h>

#define T_TOK 32768
#define D_DIM 128
#define E_EXP 32
#define K_TOP 8
#define DFF_DIM 512
#define TILE 128          // tokens per ffn block
#define NCHUNK 8          // DFF chunks of 64

typedef __attribute__((ext_vector_type(8)))  short s16x8;
typedef __attribute__((ext_vector_type(4)))  float f32x4;
typedef __attribute__((ext_vector_type(16))) float f32x16;

__device__ inline unsigned short f2bf(float f) {
    union { float f; unsigned u; } v; v.f = f;
    unsigned r = (v.u + 0x7fffu + ((v.u >> 16) & 1u)) >> 16;
    return (unsigned short)r;
}

__device__ __forceinline__ void gld16(const unsigned short* g, unsigned short* l) {
    __builtin_amdgcn_global_load_lds(
        (const __attribute__((address_space(1))) void*)g,
        (__attribute__((address_space(3))) void*)l, 16, 0, 0);
}

// ---------------- convert: x -> bf16, W1/W2 -> 32x32x16 fragment-linear bf16 ----------------
// W1t frag: (((e*8+fc)*2 + n)*8 + ks)*64 + l ; elem j = W1[e][d=ks*16+(l>>5)*8+j][f=fc*64+n*32+(l&31)]
// W2t frag: (((e*8+fc)*4 + dt)*4 + ks2)*64 + l; elem j = W2[e][f=fc*64+ks2*16+(l>>5)*8+j][dout=dt*32+(l&31)]
extern "C" __global__ __launch_bounds__(256)
void moe_convert(const float* __restrict__ x, const float* __restrict__ W1,
                 const float* __restrict__ W2, unsigned short* __restrict__ xb,
                 unsigned short* __restrict__ W1t, unsigned short* __restrict__ W2t)
{
    const int b = blockIdx.x, t = threadIdx.x;
    if (b < 2048) {
        const size_t i0 = ((size_t)b * 256 + t) * 8;
        const float4 a = *reinterpret_cast<const float4*>(x + i0);
        const float4 c = *reinterpret_cast<const float4*>(x + i0 + 4);
        s16x8 v;
        v[0]=(short)f2bf(a.x); v[1]=(short)f2bf(a.y); v[2]=(short)f2bf(a.z); v[3]=(short)f2bf(a.w);
        v[4]=(short)f2bf(c.x); v[5]=(short)f2bf(c.y); v[6]=(short)f2bf(c.z); v[7]=(short)f2bf(c.w);
        *reinterpret_cast<s16x8*>(xb + i0) = v;
    } else if (b < 3072) {
        const int t2 = (b - 2048) * 256 + t;     // 0..262143
        const int l  = t2 & 63;
        const int ks = (t2 >> 6) & 7;
        const int n  = (t2 >> 9) & 1;
        const int fc = (t2 >> 10) & 7;
        const int e  = t2 >> 13;
        const int f  = fc * 64 + n * 32 + (l & 31);
        const int d0 = ks * 16 + (l >> 5) * 8;
        s16x8 v;
        #pragma unroll
        for (int j = 0; j < 8; ++j)
            v[j] = (short)f2bf(W1[((size_t)e * D_DIM + d0 + j) * DFF_DIM + f]);
        *reinterpret_cast<s16x8*>(W1t + (size_t)t2 * 8) = v;
    } else {
        const int t2 = (b - 3072) * 256 + t;
        const int l   = t2 & 63;
        const int ks2 = (t2 >> 6) & 3;
        const int dt  = (t2 >> 8) & 3;
        const int fc  = (t2 >> 10) & 7;
        const int e   = t2 >> 13;
        const int dout = dt * 32 + (l & 31);
        const int f0   = fc * 64 + ks2 * 16 + (l >> 5) * 8;
        s16x8 v;
        #pragma unroll
        for (int j = 0; j < 8; ++j)
            v[j] = (short)f2bf(W2[((size_t)e * DFF_DIM + f0 + j) * D_DIM + dout]);
        *reinterpret_cast<s16x8*>(W2t + (size_t)t2 * 8) = v;
    }
}

// ---------------- Router (unchanged; packs t*8+k) ----------------
extern "C" __global__ __launch_bounds__(256)
void moe_router(const float* __restrict__ x, const float* __restrict__ Wr,
                const float* __restrict__ br, int* __restrict__ g_cnt,
                int* __restrict__ list_tok, float* __restrict__ list_gate)
{
    __shared__ float Wrs[E_EXP * D_DIM];
    __shared__ float brs[E_EXP];
    __shared__ int cnt_s[E_EXP];
    __shared__ int base_s[E_EXP];
    const int tid = threadIdx.x;
    for (int i = tid; i < E_EXP * D_DIM; i += 256) Wrs[i] = Wr[i];
    if (tid < E_EXP) { brs[tid] = br[tid]; cnt_s[tid] = 0; }
    __syncthreads();

    const int t = blockIdx.x * 256 + tid;
    float logits[E_EXP];
    #pragma unroll
    for (int e = 0; e < E_EXP; ++e) logits[e] = brs[e];

    const float4* xr = reinterpret_cast<const float4*>(x + (size_t)t * D_DIM);
    for (int dc = 0; dc < D_DIM / 4; ++dc) {
        const float4 xv = xr[dc];
        #pragma unroll
        for (int e = 0; e < E_EXP; ++e) {
            const float4 wv = reinterpret_cast<const float4*>(Wrs + e * D_DIM)[dc];
            logits[e] = fmaf(xv.x, wv.x, fmaf(xv.y, wv.y, fmaf(xv.z, wv.z, fmaf(xv.w, wv.w, logits[e]))));
        }
    }

    float vals[K_TOP]; int ids[K_TOP];
    #pragma unroll
    for (int k = 0; k < K_TOP; ++k) {
        float m = -3e38f; int mi = 0;
        #pragma unroll
        for (int e = 0; e < E_EXP; ++e) if (logits[e] > m) { m = logits[e]; mi = e; }
        vals[k] = m; ids[k] = mi;
        #pragma unroll
        for (int e = 0; e < E_EXP; ++e) if (e == mi) logits[e] = -3e38f;
    }
    float s = 0.f, w[K_TOP];
    #pragma unroll
    for (int k = 0; k < K_TOP; ++k) { w[k] = expf(vals[k] - vals[0]); s += w[k]; }
    const float inv = 1.f / s;

    int pos[K_TOP];
    #pragma unroll
    for (int k = 0; k < K_TOP; ++k) pos[k] = atomicAdd(&cnt_s[ids[k]], 1);
    __syncthreads();
    if (tid < E_EXP) base_s[tid] = atomicAdd(&g_cnt[tid], cnt_s[tid]);
    __syncthreads();
    #pragma unroll
    for (int k = 0; k < K_TOP; ++k) {
        const int e = ids[k];
        const int p = base_s[e] + pos[k];
        list_tok[e * T_TOK + p]  = t * 8 + k;
        list_gate[e * T_TOK + p] = w[k] * inv;
    }
}

// ---------------- MFMA expert FFN: dbuf W + raw barriers + counted waits ----------------
extern "C" __global__ __launch_bounds__(512, 4)
void moe_ffn(const unsigned short* __restrict__ xb,
             const unsigned short* __restrict__ W1t,
             const unsigned short* __restrict__ W2t,
             const float* __restrict__ b1, const float* __restrict__ b2,
             const int* __restrict__ g_cnt, const int* __restrict__ list_tok,
             const float* __restrict__ list_gate, float* __restrict__ slots)
{
    const int lin   = blockIdx.x;
    const int e     = (lin & 7) * 4 + ((lin >> 3) & 3);
    const int tile0 = (lin >> 5) * TILE;
    const int cnt   = g_cnt[e];
    if (tile0 >= cnt) return;

    __shared__ unsigned short WsA[2][8192];  // W1 chunk dbuf, 32 KB
    __shared__ unsigned short WsB[2][8192];  // W2 chunk dbuf, 32 KB
    __shared__ unsigned short Hs[8192];      // H [tok128][f64], swizzled, 16 KB

    const int tid  = threadIdx.x;
    const int w    = tid >> 6;
    const int lane = tid & 63;
    const int h    = lane >> 5;
    const int l31  = lane & 31;
    const int wf   = w & 1;
    const int wtok = w >> 1;
    const int o0   = w * 64;          // frag slots w and 8+w
    const int o1   = (8 + w) * 64;

    const int gt    = tile0 + wtok * 32 + l31;
    const bool valid = gt < cnt;
    int entry = 0; float gate = 0.f;
    if (valid) { entry = list_tok[e * T_TOK + gt]; gate = list_gate[e * T_TOK + gt]; }
    const int tokid = entry >> 3;

    const unsigned short* w1src = W1t + (size_t)e * 8 * 8192;
    const unsigned short* w2src = W2t + (size_t)e * 8 * 8192;

    // ---- stage(0) into buf 0 ----
    gld16(w1src + (size_t)(o0 + lane) * 8, WsA[0] + o0 * 8);
    gld16(w1src + (size_t)(o1 + lane) * 8, WsA[0] + o1 * 8);
    gld16(w2src + (size_t)(o0 + lane) * 8, WsB[0] + o0 * 8);
    gld16(w2src + (size_t)(o1 + lane) * 8, WsB[0] + o1 * 8);

    // ---- X fragments into registers ----
    s16x8 xf[8];
    #pragma unroll
    for (int ks = 0; ks < 8; ++ks) {
        s16x8 v = {0,0,0,0,0,0,0,0};
        if (valid)
            v = *reinterpret_cast<const s16x8*>(xb + (size_t)tokid * D_DIM + ks * 16 + h * 8);
        xf[ks] = v;
    }

    f32x16 acc2a = {0,0,0,0,0,0,0,0,0,0,0,0,0,0,0,0};
    f32x16 acc2b = {0,0,0,0,0,0,0,0,0,0,0,0,0,0,0,0};
    const int hrow = wtok * 32 + l31;
    char* hbase = reinterpret_cast<char*>(Hs) + hrow * 128;
    const int hx = hrow & 7;

    int buf = 0;
    for (int fc = 0; fc < NCHUNK; ++fc) {
        // stage(fc) was issued a full chunk ago — drain it, then sync
        asm volatile("s_waitcnt vmcnt(0)" ::: "memory");
        __builtin_amdgcn_sched_barrier(0);
        __builtin_amdgcn_s_barrier();      // all waves' stage(fc) landed; buf^1 free
        __builtin_amdgcn_sched_barrier(0);

        if (fc < NCHUNK - 1) {             // stage(fc+1) -> buf^1, stays in flight all chunk
            const unsigned short* s1 = w1src + (size_t)(fc + 1) * 8192;
            const unsigned short* s2 = w2src + (size_t)(fc + 1) * 8192;
            unsigned short* dA = WsA[buf ^ 1];
            unsigned short* dB = WsB[buf ^ 1];
            gld16(s1 + (size_t)(o0 + lane) * 8, dA + o0 * 8);
            gld16(s1 + (size_t)(o1 + lane) * 8, dA + o1 * 8);
            gld16(s2 + (size_t)(o0 + lane) * 8, dB + o0 * 8);
            gld16(s2 + (size_t)(o1 + lane) * 8, dB + o1 * 8);
        }

        // ---- GEMM1: acc1[f32][tok32] over d=128 ----
        const unsigned short* A = WsA[buf];
        f32x16 acc1 = {0,0,0,0,0,0,0,0,0,0,0,0,0,0,0,0};
        #pragma unroll
        for (int ks = 0; ks < 8; ++ks) {
            const s16x8 a = *reinterpret_cast<const s16x8*>(A + ((wf * 8 + ks) * 64 + lane) * 8);
            acc1 = __builtin_amdgcn_mfma_f32_32x32x16_bf16(a, xf[ks], acc1, 0, 0, 0);
        }

        // ---- bias + relu + pack -> Hs ----
        #pragma unroll
        for (int rq = 0; rq < 4; ++rq) {
            const f32x4 b1v = *reinterpret_cast<const f32x4*>(
                b1 + (size_t)e * DFF_DIM + fc * 64 + wf * 32 + rq * 8 + h * 4);
            const float v0 = fmaxf(acc1[4*rq+0] + b1v[0], 0.f);
            const float v1 = fmaxf(acc1[4*rq+1] + b1v[1], 0.f);
            const float v2 = fmaxf(acc1[4*rq+2] + b1v[2], 0.f);
            const float v3 = fmaxf(acc1[4*rq+3] + b1v[3], 0.f);
            const unsigned p0 = (unsigned)f2bf(v0) | ((unsigned)f2bf(v1) << 16);
            const unsigned p1 = (unsigned)f2bf(v2) | ((unsigned)f2bf(v3) << 16);
            *reinterpret_cast<uint2*>(hbase + (((wf * 4 + rq) ^ hx) * 16) + h * 8) =
                make_uint2(p0, p1);
        }

        // Hs visibility only — W prefetch stays in flight (no vmcnt here)
        asm volatile("s_waitcnt lgkmcnt(0)" ::: "memory");
        __builtin_amdgcn_sched_barrier(0);
        __builtin_amdgcn_s_barrier();
        __builtin_amdgcn_sched_barrier(0);

        // ---- GEMM2: acc2 over f=64, accumulated across chunks ----
        const unsigned short* B = WsB[buf];
        #pragma unroll
        for (int ks2 = 0; ks2 < 4; ++ks2) {
            const s16x8 bh = *reinterpret_cast<const s16x8*>(
                hbase + (((ks2 * 2 + h) ^ hx) * 16));
            const s16x8 aw0 = *reinterpret_cast<const s16x8*>(
                B + (((wf * 2 + 0) * 4 + ks2) * 64 + lane) * 8);
            const s16x8 aw1 = *reinterpret_cast<const s16x8*>(
                B + (((wf * 2 + 1) * 4 + ks2) * 64 + lane) * 8);
            acc2a = __builtin_amdgcn_mfma_f32_32x32x16_bf16(aw0, bh, acc2a, 0, 0, 0);
            acc2b = __builtin_amdgcn_mfma_f32_32x32x16_bf16(aw1, bh, acc2b, 0, 0, 0);
        }
        buf ^= 1;
    }

    // ---- epilogue: slots[entry][dout] = gate * (acc2 + b2) ----
    if (valid) {
        float* srow = slots + (size_t)entry * D_DIM;
        #pragma unroll
        for (int q = 0; q < 2; ++q) {
            #pragma unroll
            for (int rq = 0; rq < 4; ++rq) {
                const int dout = (wf * 2 + q) * 32 + rq * 8 + h * 4;
                const f32x4 b2v = *reinterpret_cast<const f32x4*>(b2 + (size_t)e * D_DIM + dout);
                f32x4 vv;
                if (q == 0) {
                    vv[0] = gate * (acc2a[4*rq+0] + b2v[0]);
                    vv[1] = gate * (acc2a[4*rq+1] + b2v[1]);
                    vv[2] = gate * (acc2a[4*rq+2] + b2v[2]);
                    vv[3] = gate * (acc2a[4*rq+3] + b2v[3]);
                } else {
                    vv[0] = gate * (acc2b[4*rq+0] + b2v[0]);
                    vv[1] = gate * (acc2b[4*rq+1] + b2v[1]);
                    vv[2] = gate * (acc2b[4*rq+2] + b2v[2]);
                    vv[3] = gate * (acc2b[4*rq+3] + b2v[3]);
                }
                *reinterpret_cast<f32x4*>(srow + dout) = vv;
            }
        }
    }
}

// ---------------- combine: out[t][d] = sum_k slots[t*8+k][d] ----------------
extern "C" __global__ __launch_bounds__(256)
void moe_combine(const float* __restrict__ slots, float* __restrict__ out)
{
    const int tid = threadIdx.x;
    const int t  = blockIdx.x * 8 + (tid >> 5);
    const int d4 = (tid & 31) * 4;
    const float* base = slots + ((size_t)t * 8) * D_DIM + d4;
    f32x4 s = *reinterpret_cast<const f32x4*>(base);
    #pragma unroll
    for (int k = 1; k < K_TOP; ++k) {
        const f32x4 v = *reinterpret_cast<const f32x4*>(base + (size_t)k * D_DIM);
        s[0] += v[0]; s[1] += v[1]; s[2] += v[2]; s[3] += v[3];
    }
    *reinterpret_cast<f32x4*>(out + (size_t)t * D_DIM + d4) = s;
}

extern "C" void kernel_launch(void* const* d_in, const int* in_sizes, int n_in,
                              void* d_out, int out_size, void* d_ws, size_t ws_size,
                              hipStream_t stream)
{
    const float* x  = (const float*)d_in[0];
    const float* Wr = (const float*)d_in[1];
    const float* br = (const float*)d_in[2];
    const float* W1 = (const float*)d_in[3];
    const float* b1 = (const float*)d_in[4];
    const float* W2 = (const float*)d_in[5];
    const float* b2 = (const float*)d_in[6];
    float* out = (float*)d_out;

    char* ws = (char*)d_ws;
    float* slots = (float*)ws;                                  // 134,217,728 B
    size_t off = (size_t)T_TOK * K_TOP * D_DIM * 4;
    int*   g_cnt     = (int*)(ws + off);                        // 256 B reserved
    int*   list_tok  = (int*)(ws + off + 256);                  // 4 MB
    float* list_gate = (float*)(ws + off + 256 + 4194304);      // 4 MB
    unsigned short* xb  = (unsigned short*)(ws + off + 256 + 8388608);               // 8 MB
    unsigned short* W1t = (unsigned short*)(ws + off + 256 + 8388608 + 8388608);     // 4 MB
    unsigned short* W2t = (unsigned short*)(ws + off + 256 + 8388608 + 8388608 + 4194304); // 4 MB

    hipMemsetAsync(g_cnt, 0, E_EXP * sizeof(int), stream);

    moe_convert<<<dim3(4096), dim3(256), 0, stream>>>(x, W1, W2, xb, W1t, W2t);
    moe_router<<<dim3(T_TOK / 256), dim3(256), 0, stream>>>(x, Wr, br, g_cnt, list_tok, list_gate);
    moe_ffn<<<dim3((T_TOK / TILE) * E_EXP), dim3(512), 0, stream>>>(xb, W1t, W2t, b1, b2, g_cnt,
                                                                    list_tok, list_gate, slots);
    moe_combine<<<dim3(T_TOK / 8), dim3(256), 0, stream>>>(slots, out);
}